// Round 5
// baseline (369.192 us; speedup 1.0000x reference)
//
#include <hip/hip_runtime.h>

#define BD  32
#define CD  16
#define HD  256
#define WD  256
#define KD  4
#define OD  16
#define C4D 4

// Module-level scratch: no dependence on ws_size (OOB-crash-proof).
// Both arrays are FULLY overwritten on every kernel_launch call.
__device__ float g_pooled[BD * CD];            // per-(b,c) plane sums
__device__ float g_agg[BD * CD * 9 * OD];      // [b][c*9+tap][o]

// ---------------- Kernel 1: global average pool ----------------------------
// grid = 512 blocks: one per (b,c) plane; 256 threads; no atomics.
__global__ void pool_kernel(const float* __restrict__ x) {
    const int plane = blockIdx.x;               // 0..511  (b*16+c)
    const float4* xp4 = reinterpret_cast<const float4*>(x + (size_t)plane * (HD * WD));

    float s = 0.f;
    #pragma unroll 4
    for (int j = threadIdx.x; j < HD * WD / 4; j += 256) {   // 64 float4 / thread
        float4 v = xp4[j];
        s += v.x + v.y + v.z + v.w;
    }

    __shared__ float red[256];
    red[threadIdx.x] = s;
    __syncthreads();
    for (int off = 128; off > 0; off >>= 1) {
        if (threadIdx.x < off) red[threadIdx.x] += red[threadIdx.x + off];
        __syncthreads();
    }
    if (threadIdx.x == 0) g_pooled[plane] = red[0];          // sum; mean applied later
}

// ---------------- Kernel 2: attention MLP + softmax + weight aggregation ---
// grid = 32 blocks (one per sample). agg layout: [b][c*9+tap][o].
__global__ void attn_agg_kernel(const float* __restrict__ w1, const float* __restrict__ b1,
                                const float* __restrict__ w2, const float* __restrict__ b2,
                                const float* __restrict__ weight) {
    const int b = blockIdx.x;

    // every thread computes attn redundantly (tiny)
    float p[CD];
    #pragma unroll
    for (int c = 0; c < CD; ++c) p[c] = g_pooled[b * CD + c] * (1.f / (HD * WD));

    float h[C4D];
    #pragma unroll
    for (int j = 0; j < C4D; ++j) {
        float s = b1[j];
        #pragma unroll
        for (int c = 0; c < CD; ++c) s = fmaf(p[c], w1[j * CD + c], s);
        h[j] = fmaxf(s, 0.f);
    }

    float lg[KD];
    float mx = -1e30f;
    #pragma unroll
    for (int k = 0; k < KD; ++k) {
        float s = b2[k];
        #pragma unroll
        for (int j = 0; j < C4D; ++j) s = fmaf(h[j], w2[k * C4D + j], s);
        lg[k] = s;
        mx = fmaxf(mx, s);
    }
    float se = 0.f;
    #pragma unroll
    for (int k = 0; k < KD; ++k) { lg[k] = expf(lg[k] - mx); se += lg[k]; }
    const float inv = 1.f / se;

    // aggregated weights, re-laid-out for broadcast LDS reads in conv
    for (int idx = threadIdx.x; idx < CD * 9 * OD; idx += 256) {
        const int o   = idx & 15;
        const int t   = idx >> 4;       // c*9 + tap
        const int c   = t / 9;
        const int tap = t - c * 9;
        float s = 0.f;
        #pragma unroll
        for (int k = 0; k < KD; ++k)
            s = fmaf(lg[k] * inv, weight[((k * OD + o) * CD + c) * 9 + tap], s);
        g_agg[b * (CD * 9 * OD) + idx] = s;
    }
}

// ---------------- Kernel 3: per-sample 3x3 conv, C=16 -> O=16 --------------
// grid = (32 row-strips, 32 samples), 256 threads. Thread = 1 column,
// 8 output rows, all 16 output channels (128 fp32 accumulators).
// T14 async-STAGE: next group's 10 float4 loads issued before current compute.
__global__ __launch_bounds__(256, 2)
void conv_kernel(const float* __restrict__ x, float* __restrict__ out) {
    const int strip = blockIdx.x;        // 0..31
    const int b     = blockIdx.y;        // 0..31
    const int ct    = threadIdx.x;       // output column 0..255
    const int r0    = strip * 8;

    // x tile: 4 channels x (8+2 halo rows) x 264 cols.
    // Data col c_x at index 4+c_x (16B-aligned float4 writes); halo at 3 / 260.
    __shared__ float xlds[4][10][264];
    __shared__ float wlds[CD * 9 * OD];  // 2304 aggregated weights, [c*9+tap][o]

    // ---- stage this sample's weights into LDS (broadcast-read later) ----
    {
        const float* wb = g_agg + b * (CD * 9 * OD);
        for (int i = threadIdx.x; i < CD * 9 * OD; i += 256) wlds[i] = wb[i];
    }
    // ---- halo columns (x cols -1 and 256) zeroed ONCE: never overwritten ----
    if (threadIdx.x < 80) {  // 4ch x 10rows x 2 halo cols
        const int ch  = threadIdx.x / 20;
        const int rem = threadIdx.x % 20;
        xlds[ch][rem >> 1][(rem & 1) ? 260 : 3] = 0.f;
    }

    float acc[8][OD];
    #pragma unroll
    for (int r = 0; r < 8; ++r)
        #pragma unroll
        for (int o = 0; o < OD; ++o) acc[r][o] = 0.f;

    // Per group: 4ch x 10rows x 64 float4 = 2560 float4; 10 per thread.
    // Static-indexed prefetch regs (rule #20: no runtime indexing).
    float4 pre[10];

    #define STAGE_LOAD(gg)                                                       \
        _Pragma("unroll")                                                        \
        for (int i = 0; i < 10; ++i) {                                           \
            const int idx = threadIdx.x + i * 256;                               \
            const int ch  = idx / 640;                                           \
            const int rem = idx - ch * 640;                                      \
            const int rr  = rem >> 6;                                            \
            const int j   = rem & 63;                                            \
            const int row = r0 - 1 + rr;                                         \
            pre[i] = make_float4(0.f, 0.f, 0.f, 0.f);                            \
            if (row >= 0 && row < HD)                                            \
                pre[i] = *reinterpret_cast<const float4*>(                       \
                    x + (size_t)(b * CD + (gg) * 4 + ch) * (HD * WD)             \
                      + row * WD + 4 * j);                                       \
        }

    #define STAGE_WRITE()                                                        \
        _Pragma("unroll")                                                        \
        for (int i = 0; i < 10; ++i) {                                           \
            const int idx = threadIdx.x + i * 256;                               \
            const int ch  = idx / 640;                                           \
            const int rem = idx - ch * 640;                                      \
            const int rr  = rem >> 6;                                            \
            const int j   = rem & 63;                                            \
            *reinterpret_cast<float4*>(&xlds[ch][rr][4 + 4 * j]) = pre[i];       \
        }

    // prologue: stage group 0
    STAGE_LOAD(0)
    STAGE_WRITE()
    __syncthreads();

    #pragma unroll 1
    for (int g = 0; g < 4; ++g) {
        if (g < 3) STAGE_LOAD(g + 1)      // issue early; latency hides under FMAs

        // ---- compute: 4 channels, 1152 FMAs each ----
        #pragma unroll 1
        for (int ch = 0; ch < 4; ++ch) {
            float xw[10][3];
            #pragma unroll
            for (int rr = 0; rr < 10; ++rr)
                #pragma unroll
                for (int kk = 0; kk < 3; ++kk)
                    xw[rr][kk] = xlds[ch][rr][ct + 3 + kk];

            // weights: uniform-address float4 broadcast reads from LDS
            const float4* wc4 = reinterpret_cast<const float4*>(&wlds[(g * 4 + ch) * 144]);
            #pragma unroll
            for (int ky = 0; ky < 3; ++ky)
                #pragma unroll
                for (int kx = 0; kx < 3; ++kx)
                    #pragma unroll
                    for (int o4 = 0; o4 < 4; ++o4) {
                        const float4 w4 = wc4[(ky * 3 + kx) * 4 + o4];
                        #pragma unroll
                        for (int r = 0; r < 8; ++r) {
                            const float xv = xw[r + ky][kx];
                            acc[r][4 * o4 + 0] = fmaf(w4.x, xv, acc[r][4 * o4 + 0]);
                            acc[r][4 * o4 + 1] = fmaf(w4.y, xv, acc[r][4 * o4 + 1]);
                            acc[r][4 * o4 + 2] = fmaf(w4.z, xv, acc[r][4 * o4 + 2]);
                            acc[r][4 * o4 + 3] = fmaf(w4.w, xv, acc[r][4 * o4 + 3]);
                        }
                    }
        }
        __syncthreads();                  // all waves done READING xlds
        if (g < 3) {
            STAGE_WRITE()                 // write-late: regs -> LDS
            __syncthreads();
        }
    }
    #undef STAGE_LOAD
    #undef STAGE_WRITE

    // ---- write out: coalesced across ct ----
    #pragma unroll
    for (int o = 0; o < OD; ++o)
        #pragma unroll
        for (int r = 0; r < 8; ++r)
            out[(((size_t)b * OD + o) * HD + (r0 + r)) * WD + ct] = acc[r][o];
}

extern "C" void kernel_launch(void* const* d_in, const int* in_sizes, int n_in,
                              void* d_out, int out_size, void* d_ws, size_t ws_size,
                              hipStream_t stream) {
    (void)in_sizes; (void)n_in; (void)out_size; (void)d_ws; (void)ws_size;
    const float* x      = (const float*)d_in[0];
    const float* weight = (const float*)d_in[1];
    const float* w1     = (const float*)d_in[2];
    const float* b1     = (const float*)d_in[3];
    const float* w2     = (const float*)d_in[4];
    const float* b2     = (const float*)d_in[5];
    float* out = (float*)d_out;

    pool_kernel<<<512, 256, 0, stream>>>(x);
    attn_agg_kernel<<<32, 256, 0, stream>>>(w1, b1, w2, b2, weight);
    conv_kernel<<<dim3(32, 32), 256, 0, stream>>>(x, out);
}

// Round 6
// 336.741 us; speedup vs baseline: 1.0964x; 1.0964x over previous
//
#include <hip/hip_runtime.h>

#define BD  32
#define CD  16
#define HD  256
#define WD  256
#define KD  4
#define OD  16
#define C4D 4

// Module-level scratch: no dependence on ws_size (OOB-crash-proof).
// Both arrays are FULLY overwritten on every kernel_launch call.
__device__ float g_pooled[BD * CD];            // per-(b,c) plane sums
__device__ float g_agg[BD * CD * 9 * OD];      // [b][c*9+tap][o]

// ---------------- Kernel 1: global average pool ----------------------------
// grid = 512 blocks: one per (b,c) plane; 256 threads; no atomics.
__global__ void pool_kernel(const float* __restrict__ x) {
    const int plane = blockIdx.x;               // 0..511  (b*16+c)
    const float4* xp4 = reinterpret_cast<const float4*>(x + (size_t)plane * (HD * WD));

    float s = 0.f;
    #pragma unroll 4
    for (int j = threadIdx.x; j < HD * WD / 4; j += 256) {   // 64 float4 / thread
        float4 v = xp4[j];
        s += v.x + v.y + v.z + v.w;
    }

    __shared__ float red[256];
    red[threadIdx.x] = s;
    __syncthreads();
    for (int off = 128; off > 0; off >>= 1) {
        if (threadIdx.x < off) red[threadIdx.x] += red[threadIdx.x + off];
        __syncthreads();
    }
    if (threadIdx.x == 0) g_pooled[plane] = red[0];          // sum; mean applied later
}

// ---------------- Kernel 2: attention MLP + softmax + weight aggregation ---
// grid = 32 blocks (one per sample). agg layout: [b][c*9+tap][o].
__global__ void attn_agg_kernel(const float* __restrict__ w1, const float* __restrict__ b1,
                                const float* __restrict__ w2, const float* __restrict__ b2,
                                const float* __restrict__ weight) {
    const int b = blockIdx.x;

    // every thread computes attn redundantly (tiny)
    float p[CD];
    #pragma unroll
    for (int c = 0; c < CD; ++c) p[c] = g_pooled[b * CD + c] * (1.f / (HD * WD));

    float h[C4D];
    #pragma unroll
    for (int j = 0; j < C4D; ++j) {
        float s = b1[j];
        #pragma unroll
        for (int c = 0; c < CD; ++c) s = fmaf(p[c], w1[j * CD + c], s);
        h[j] = fmaxf(s, 0.f);
    }

    float lg[KD];
    float mx = -1e30f;
    #pragma unroll
    for (int k = 0; k < KD; ++k) {
        float s = b2[k];
        #pragma unroll
        for (int j = 0; j < C4D; ++j) s = fmaf(h[j], w2[k * C4D + j], s);
        lg[k] = s;
        mx = fmaxf(mx, s);
    }
    float se = 0.f;
    #pragma unroll
    for (int k = 0; k < KD; ++k) { lg[k] = expf(lg[k] - mx); se += lg[k]; }
    const float inv = 1.f / se;

    // aggregated weights, re-laid-out for broadcast LDS reads in conv
    for (int idx = threadIdx.x; idx < CD * 9 * OD; idx += 256) {
        const int o   = idx & 15;
        const int t   = idx >> 4;       // c*9 + tap
        const int c   = t / 9;
        const int tap = t - c * 9;
        float s = 0.f;
        #pragma unroll
        for (int k = 0; k < KD; ++k)
            s = fmaf(lg[k] * inv, weight[((k * OD + o) * CD + c) * 9 + tap], s);
        g_agg[b * (CD * 9 * OD) + idx] = s;
    }
}

// ---------------- Kernel 3: per-sample 3x3 conv, C=16 -> O=16 --------------
// grid = (64 row-strips, 32 samples), 256 threads. Thread = 1 column,
// 4 output rows, all 16 output channels (64 fp32 accumulators).
// De-spilled vs R5: acc 128->64 regs, no prefetch regs; demand ~110 < 128
// so the allocator fits 4 waves/SIMD without scratch.
__global__ __launch_bounds__(256, 3)
void conv_kernel(const float* __restrict__ x, float* __restrict__ out) {
    const int strip = blockIdx.x;        // 0..63
    const int b     = blockIdx.y;        // 0..31
    const int ct    = threadIdx.x;       // output column 0..255
    const int r0    = strip * 4;

    // x tile: 4 channels x (4+2 halo rows) x 264 cols.
    // Data col c_x at index 4+c_x (16B-aligned float4 writes); halo at 3 / 260.
    __shared__ float xlds[4][6][264];    // 25.3 KiB
    __shared__ float wlds[CD * 9 * OD];  // 9.2 KiB: [c*9+tap][o]

    // ---- stage this sample's weights into LDS (broadcast-read later) ----
    {
        const float* wb = g_agg + b * (CD * 9 * OD);
        for (int i = threadIdx.x; i < CD * 9 * OD; i += 256) wlds[i] = wb[i];
    }
    // ---- halo columns (x cols -1 and 256) zeroed ONCE: never overwritten ----
    if (threadIdx.x < 48) {  // 4ch x 6rows x 2 halo cols
        const int ch  = threadIdx.x / 12;
        const int rem = threadIdx.x % 12;
        xlds[ch][rem >> 1][(rem & 1) ? 260 : 3] = 0.f;
    }

    float acc[4][OD];
    #pragma unroll
    for (int r = 0; r < 4; ++r)
        #pragma unroll
        for (int o = 0; o < OD; ++o) acc[r][o] = 0.f;

    // Stage: per group 4ch x 6rows x 64 float4 = 1536 float4; 6 per thread.
    #define STAGE(gg)                                                            \
        _Pragma("unroll")                                                        \
        for (int i = 0; i < 6; ++i) {                                            \
            const int idx    = threadIdx.x + i * 256;                            \
            const int rowIdx = idx >> 6;         /* 0..23 */                     \
            const int j      = idx & 63;                                         \
            const int ch     = rowIdx / 6;                                       \
            const int rr     = rowIdx - ch * 6;                                  \
            const int row    = r0 - 1 + rr;                                      \
            float4 v = make_float4(0.f, 0.f, 0.f, 0.f);                          \
            if (row >= 0 && row < HD)                                            \
                v = *reinterpret_cast<const float4*>(                            \
                    x + (size_t)(b * CD + (gg) * 4 + ch) * (HD * WD)             \
                      + row * WD + 4 * j);                                       \
            *reinterpret_cast<float4*>(&xlds[ch][rr][4 + 4 * j]) = v;            \
        }

    STAGE(0)
    __syncthreads();

    #pragma unroll 1
    for (int g = 0; g < 4; ++g) {
        // ---- compute: 4 channels, 576 FMAs each ----
        #pragma unroll 1
        for (int ch = 0; ch < 4; ++ch) {
            float xw[6][3];
            #pragma unroll
            for (int rr = 0; rr < 6; ++rr)
                #pragma unroll
                for (int kk = 0; kk < 3; ++kk)
                    xw[rr][kk] = xlds[ch][rr][ct + 3 + kk];

            // weights: uniform-address float4 broadcast reads from LDS
            const float4* wc4 = reinterpret_cast<const float4*>(&wlds[(g * 4 + ch) * 144]);
            #pragma unroll
            for (int ky = 0; ky < 3; ++ky)
                #pragma unroll
                for (int kx = 0; kx < 3; ++kx)
                    #pragma unroll
                    for (int o4 = 0; o4 < 4; ++o4) {
                        const float4 w4 = wc4[(ky * 3 + kx) * 4 + o4];
                        #pragma unroll
                        for (int r = 0; r < 4; ++r) {
                            const float xv = xw[r + ky][kx];
                            acc[r][4 * o4 + 0] = fmaf(w4.x, xv, acc[r][4 * o4 + 0]);
                            acc[r][4 * o4 + 1] = fmaf(w4.y, xv, acc[r][4 * o4 + 1]);
                            acc[r][4 * o4 + 2] = fmaf(w4.z, xv, acc[r][4 * o4 + 2]);
                            acc[r][4 * o4 + 3] = fmaf(w4.w, xv, acc[r][4 * o4 + 3]);
                        }
                    }
        }
        __syncthreads();                  // all waves done READING xlds
        if (g < 3) {
            STAGE(g + 1)                  // overlap across 4 resident blocks/CU
            __syncthreads();
        }
    }
    #undef STAGE

    // ---- write out: coalesced across ct ----
    #pragma unroll
    for (int o = 0; o < OD; ++o)
        #pragma unroll
        for (int r = 0; r < 4; ++r)
            out[(((size_t)b * OD + o) * HD + (r0 + r)) * WD + ct] = acc[r][o];
}

extern "C" void kernel_launch(void* const* d_in, const int* in_sizes, int n_in,
                              void* d_out, int out_size, void* d_ws, size_t ws_size,
                              hipStream_t stream) {
    (void)in_sizes; (void)n_in; (void)out_size; (void)d_ws; (void)ws_size;
    const float* x      = (const float*)d_in[0];
    const float* weight = (const float*)d_in[1];
    const float* w1     = (const float*)d_in[2];
    const float* b1     = (const float*)d_in[3];
    const float* w2     = (const float*)d_in[4];
    const float* b2     = (const float*)d_in[5];
    float* out = (float*)d_out;

    pool_kernel<<<512, 256, 0, stream>>>(x);
    attn_agg_kernel<<<32, 256, 0, stream>>>(w1, b1, w2, b2, weight);
    conv_kernel<<<dim3(64, 32), 256, 0, stream>>>(x, out);
}

// Round 7
// 325.378 us; speedup vs baseline: 1.1347x; 1.0349x over previous
//
#include <hip/hip_runtime.h>

#define BD  32
#define CD  16
#define HD  256
#define WD  256
#define KD  4
#define OD  16
#define C4D 4

typedef __attribute__((ext_vector_type(8))) short short8v;   // 8 bf16 = 4 VGPR
typedef __attribute__((ext_vector_type(4))) float float4v;   // MFMA C/D

// Module-level scratch (no ws_size dependence). Fully overwritten every call.
__device__ float          g_pooled[BD * CD];
// Weight fragments in exact MFMA-B lane order: [b][prod(hi/lo)][kstep 5][lane 64][i 8]
__device__ unsigned short g_wfrag[BD * 2 * 5 * 64 * 8];

__device__ __forceinline__ unsigned short bf16_rne(float f) {
    unsigned u = __builtin_bit_cast(unsigned, f);
    u += 0x7FFFu + ((u >> 16) & 1u);
    return (unsigned short)(u >> 16);
}
__device__ __forceinline__ float bf16_to_f(unsigned short h) {
    unsigned u = ((unsigned)h) << 16;
    return __builtin_bit_cast(float, u);
}

// ---------------- Kernel 1: global average pool (unchanged, proven) --------
__global__ void pool_kernel(const float* __restrict__ x) {
    const int plane = blockIdx.x;               // 0..511  (b*16+c)
    const float4* xp4 = reinterpret_cast<const float4*>(x + (size_t)plane * (HD * WD));

    float s = 0.f;
    #pragma unroll 4
    for (int j = threadIdx.x; j < HD * WD / 4; j += 256) {
        float4 v = xp4[j];
        s += v.x + v.y + v.z + v.w;
    }

    __shared__ float red[256];
    red[threadIdx.x] = s;
    __syncthreads();
    for (int off = 128; off > 0; off >>= 1) {
        if (threadIdx.x < off) red[threadIdx.x] += red[threadIdx.x + off];
        __syncthreads();
    }
    if (threadIdx.x == 0) g_pooled[plane] = red[0];
}

// ---------------- Kernel 2: attn MLP + softmax + bf16 weight fragments -----
// K-packing: kstep s covers K=32 = taps {2s, 2s+1} x 16 channels; tap 9 = zero pad.
// B-frag lane map (16x16x32): o = lane&15, kk = (lane>>4)*8 + i.
__global__ void attn_agg_kernel(const float* __restrict__ w1, const float* __restrict__ b1,
                                const float* __restrict__ w2, const float* __restrict__ b2,
                                const float* __restrict__ weight) {
    const int b = blockIdx.x;

    float p[CD];
    #pragma unroll
    for (int c = 0; c < CD; ++c) p[c] = g_pooled[b * CD + c] * (1.f / (HD * WD));

    float h[C4D];
    #pragma unroll
    for (int j = 0; j < C4D; ++j) {
        float s = b1[j];
        #pragma unroll
        for (int c = 0; c < CD; ++c) s = fmaf(p[c], w1[j * CD + c], s);
        h[j] = fmaxf(s, 0.f);
    }

    float lg[KD];
    float mx = -1e30f;
    #pragma unroll
    for (int k = 0; k < KD; ++k) {
        float s = b2[k];
        #pragma unroll
        for (int j = 0; j < C4D; ++j) s = fmaf(h[j], w2[k * C4D + j], s);
        lg[k] = s;
        mx = fmaxf(mx, s);
    }
    float se = 0.f;
    #pragma unroll
    for (int k = 0; k < KD; ++k) { lg[k] = expf(lg[k] - mx); se += lg[k]; }
    const float inv = 1.f / se;
    float at[KD];
    #pragma unroll
    for (int k = 0; k < KD; ++k) at[k] = lg[k] * inv;

    // 5120 fragment elements per sample: e = ((prod*5 + s)*64 + lane)*8 + i
    for (int e = threadIdx.x; e < 5120; e += 256) {
        const int prod = e / 2560;
        const int rem  = e % 2560;
        const int s    = rem / 512;
        const int lr   = rem % 512;
        const int lane = lr >> 3;
        const int i    = lr & 7;
        const int o    = lane & 15;
        const int kg   = lane >> 4;
        const int kk   = kg * 8 + i;        // K index within step: 0..31
        const int tl   = kk >> 4;           // tap_local 0/1
        const int c    = kk & 15;
        const int tap  = 2 * s + tl;        // 0..9 (9 = padding)
        float v = 0.f;
        if (tap < 9) {
            #pragma unroll
            for (int k = 0; k < KD; ++k)
                v = fmaf(at[k], weight[((k * OD + o) * CD + c) * 9 + tap], v);
        }
        const unsigned short hi = bf16_rne(v);
        unsigned short val = hi;
        if (prod == 1) val = bf16_rne(v - bf16_to_f(hi));
        g_wfrag[b * 5120 + e] = val;
    }
}

// ---------------- Kernel 3: MFMA conv (3-product bf16 split) ---------------
// Block = one 16x16 pixel region of one sample. 4 waves; wave w computes rows
// w*4..w*4+3, each row = one 16x16x32-MFMA tile (M=16 px, N=16 o, K=144 packed).
// LDS: 18x18 halo'd pixel records, 80 B each: [hi c0-7][hi c8-15][lo c0-7][lo c8-15][pad]
// (dword stride 20 -> 16-lane b128 fragment reads are exactly 2-way = free).
__global__ __launch_bounds__(256, 3)
void conv_kernel(const float* __restrict__ x, float* __restrict__ out) {
    const int b  = blockIdx.y;
    const int tx = blockIdx.x & 15;
    const int ty = blockIdx.x >> 4;
    const int x0 = tx * 16, y0 = ty * 16;

    __shared__ unsigned short xs[18 * 18 * 40];   // 25,920 B

    // ---- stage: 16c x 18x18 fp32 -> bf16 hi/lo interleaved records ----
    for (int e = threadIdx.x; e < 5184; e += 256) {
        const int c   = e / 324;
        const int rem = e % 324;
        const int r   = rem / 18;
        const int col = rem % 18;
        const int gy  = y0 - 1 + r;
        const int gx  = x0 - 1 + col;
        float v = 0.f;
        if (gy >= 0 && gy < HD && gx >= 0 && gx < WD)
            v = x[((size_t)(b * CD + c) * HD + gy) * WD + gx];
        const unsigned short hi = bf16_rne(v);
        const unsigned short lo = bf16_rne(v - bf16_to_f(hi));
        const int base = (r * 18 + col) * 40 + (c >> 3) * 8 + (c & 7);
        xs[base]      = hi;   // hi chunk
        xs[base + 16] = lo;   // lo chunk (+32 B)
    }

    const int lane = threadIdx.x & 63;
    const int wv   = threadIdx.x >> 6;

    // ---- weight fragments: registers, straight from g_wfrag ----
    short8v whi[5], wlo[5];
    {
        const unsigned short* wf = g_wfrag + b * 5120;
        #pragma unroll
        for (int s = 0; s < 5; ++s) {
            whi[s] = *(const short8v*)&wf[s * 512 + lane * 8];
            wlo[s] = *(const short8v*)&wf[2560 + s * 512 + lane * 8];
        }
    }

    // ---- per-lane A-fragment addressing ----
    // A lane map (16x16x32): m = lane&15 (pixel), kk = (lane>>4)*8+i.
    const int m     = lane & 15;
    const int kg    = lane >> 4;
    const int tl    = kg >> 1;            // tap_local
    const int chalf = kg & 1;             // channel half (c0-7 / c8-15)
    int aoff[5];
    #pragma unroll
    for (int s = 0; s < 5; ++s) {
        int tap = 2 * s + tl;
        if (tap > 8) tap = 8;             // pad-tap reads valid data; weights are 0
        const int dy = tap / 3 - 1, dx = tap % 3 - 1;
        aoff[s] = (dy * 18 + dx) * 40;    // u16 units
    }

    __syncthreads();

    // ---- compute: 4 tiles (rows) per wave ----
    #pragma unroll
    for (int q = 0; q < 4; ++q) {
        const int rl   = wv * 4 + q;                       // local row 0..15
        const int pix0 = ((rl + 1) * 18 + (1 + m)) * 40 + chalf * 8;
        float4v acc = {0.f, 0.f, 0.f, 0.f};
        #pragma unroll
        for (int s = 0; s < 5; ++s) {
            const short8v ahi = *(const short8v*)&xs[pix0 + aoff[s]];
            const short8v alo = *(const short8v*)&xs[pix0 + aoff[s] + 16];
            acc = __builtin_amdgcn_mfma_f32_16x16x32_bf16(ahi, whi[s], acc, 0, 0, 0);
            acc = __builtin_amdgcn_mfma_f32_16x16x32_bf16(alo, whi[s], acc, 0, 0, 0);
            acc = __builtin_amdgcn_mfma_f32_16x16x32_bf16(ahi, wlo[s], acc, 0, 0, 0);
        }
        // D layout: o = lane&15, px = (lane>>4)*4 + reg -> one float4 per lane
        const int o = lane & 15;
        const int y = y0 + rl;
        float4 v4 = make_float4(acc[0], acc[1], acc[2], acc[3]);
        *reinterpret_cast<float4*>(
            &out[((size_t)(b * OD + o) * HD + y) * WD + x0 + kg * 4]) = v4;
    }
}

extern "C" void kernel_launch(void* const* d_in, const int* in_sizes, int n_in,
                              void* d_out, int out_size, void* d_ws, size_t ws_size,
                              hipStream_t stream) {
    (void)in_sizes; (void)n_in; (void)out_size; (void)d_ws; (void)ws_size;
    const float* x      = (const float*)d_in[0];
    const float* weight = (const float*)d_in[1];
    const float* w1     = (const float*)d_in[2];
    const float* b1     = (const float*)d_in[3];
    const float* w2     = (const float*)d_in[4];
    const float* b2     = (const float*)d_in[5];
    float* out = (float*)d_out;

    pool_kernel<<<512, 256, 0, stream>>>(x);
    attn_agg_kernel<<<32, 256, 0, stream>>>(w1, b1, w2, b2, weight);
    conv_kernel<<<dim3(256, 32), 256, 0, stream>>>(x, out);
}

// Round 8
// 299.810 us; speedup vs baseline: 1.2314x; 1.0853x over previous
//
#include <hip/hip_runtime.h>

#define BD  32
#define CD  16
#define HD  256
#define WD  256
#define KD  4
#define OD  16
#define C4D 4

typedef __attribute__((ext_vector_type(8))) short short8v;   // 8 bf16 = 4 VGPR
typedef __attribute__((ext_vector_type(4))) float float4v;   // MFMA C/D

// Module-level scratch (no ws_size dependence). Fully overwritten every call.
__device__ float          g_partial[2048];                   // 4 partial sums per (b,c) plane
// Weight fragments in exact MFMA-B lane order: [b][prod(hi/lo)][kstep 5][lane 64][i 8]
__device__ unsigned short g_wfrag[BD * 2 * 5 * 64 * 8];

__device__ __forceinline__ unsigned short bf16_rne(float f) {
    unsigned u = __builtin_bit_cast(unsigned, f);
    u += 0x7FFFu + ((u >> 16) & 1u);
    return (unsigned short)(u >> 16);
}
__device__ __forceinline__ float bf16_to_f(unsigned short h) {
    unsigned u = ((unsigned)h) << 16;
    return __builtin_bit_cast(float, u);
}

// ---------------- Kernel 1: global average pool ----------------------------
// 2048 blocks (4 per plane), 16 fully-unrolled float4 loads/thread -> deep ILP.
__global__ void pool_kernel(const float* __restrict__ x) {
    const int plane = blockIdx.x >> 2;          // 0..511  (b*16+c)
    const int part  = blockIdx.x & 3;
    const float4* xp4 = reinterpret_cast<const float4*>(
        x + (size_t)plane * (HD * WD) + part * (HD * WD / 4));

    float4 v[16];
    #pragma unroll
    for (int i = 0; i < 16; ++i) v[i] = xp4[threadIdx.x + i * 256];
    float s = 0.f;
    #pragma unroll
    for (int i = 0; i < 16; ++i) s += (v[i].x + v[i].y) + (v[i].z + v[i].w);

    __shared__ float red[256];
    red[threadIdx.x] = s;
    __syncthreads();
    for (int off = 128; off > 0; off >>= 1) {
        if (threadIdx.x < off) red[threadIdx.x] += red[threadIdx.x + off];
        __syncthreads();
    }
    if (threadIdx.x == 0) g_partial[blockIdx.x] = red[0];
}

// ---------------- Kernel 2: attn MLP + softmax + bf16 weight fragments -----
// K-packing: kstep s covers K=32 = taps {2s, 2s+1} x 16 channels; tap 9 = zero pad.
// B-frag lane map (16x16x32, HW-verified R7): o = lane&15, kk = (lane>>4)*8 + i.
__global__ void attn_agg_kernel(const float* __restrict__ w1, const float* __restrict__ b1,
                                const float* __restrict__ w2, const float* __restrict__ b2,
                                const float* __restrict__ weight) {
    const int b = blockIdx.x;

    float p[CD];
    #pragma unroll
    for (int c = 0; c < CD; ++c) {
        const int i0 = (b * CD + c) * 4;
        p[c] = (g_partial[i0] + g_partial[i0 + 1] + g_partial[i0 + 2] + g_partial[i0 + 3])
               * (1.f / (HD * WD));
    }

    float h[C4D];
    #pragma unroll
    for (int j = 0; j < C4D; ++j) {
        float s = b1[j];
        #pragma unroll
        for (int c = 0; c < CD; ++c) s = fmaf(p[c], w1[j * CD + c], s);
        h[j] = fmaxf(s, 0.f);
    }

    float lg[KD];
    float mx = -1e30f;
    #pragma unroll
    for (int k = 0; k < KD; ++k) {
        float s = b2[k];
        #pragma unroll
        for (int j = 0; j < C4D; ++j) s = fmaf(h[j], w2[k * C4D + j], s);
        lg[k] = s;
        mx = fmaxf(mx, s);
    }
    float se = 0.f;
    #pragma unroll
    for (int k = 0; k < KD; ++k) { lg[k] = expf(lg[k] - mx); se += lg[k]; }
    const float inv = 1.f / se;
    float at[KD];
    #pragma unroll
    for (int k = 0; k < KD; ++k) at[k] = lg[k] * inv;

    // 5120 fragment elements per sample: e = ((prod*5 + s)*64 + lane)*8 + i
    for (int e = threadIdx.x; e < 5120; e += 256) {
        const int prod = e / 2560;
        const int rem  = e % 2560;
        const int s    = rem / 512;
        const int lr   = rem % 512;
        const int lane = lr >> 3;
        const int i    = lr & 7;
        const int o    = lane & 15;
        const int kg   = lane >> 4;
        const int kk   = kg * 8 + i;        // K index within step: 0..31
        const int tl   = kk >> 4;           // tap_local 0/1
        const int c    = kk & 15;
        const int tap  = 2 * s + tl;        // 0..9 (9 = padding)
        float v = 0.f;
        if (tap < 9) {
            #pragma unroll
            for (int k = 0; k < KD; ++k)
                v = fmaf(at[k], weight[((k * OD + o) * CD + c) * 9 + tap], v);
        }
        const unsigned short hi = bf16_rne(v);
        unsigned short val = hi;
        if (prod == 1) val = bf16_rne(v - bf16_to_f(hi));
        g_wfrag[b * 5120 + e] = val;
    }
}

// ---------------- Kernel 3: MFMA conv, 2-product (xhi*whi + xhi*wlo) -------
// Block = 16 rows x 64 cols of one sample. LDS: 18x66 pixel records of 48 B
// ([hi c0-7][hi c8-15][pad16]); slot index = 3*pix + k -> bank-uniform for
// both b128 staging writes and b128 fragment reads (3m mod 8 covers evenly).
// 4 waves: wave w owns cols 16w..16w+15, all 16 rows; paired rows = 2 acc
// chains to hide dependent-MFMA latency.
__global__ __launch_bounds__(256, 2)
void conv_kernel(const float* __restrict__ x, float* __restrict__ out) {
    const int b  = blockIdx.y;
    const int tx = blockIdx.x & 3;        // 64-col strip
    const int ty = blockIdx.x >> 2;       // 16-row strip
    const int x0 = tx * 64, y0 = ty * 16;

    __shared__ unsigned short xs[18 * 66 * 24];   // 57,024 B

    // ---- stage: per pixel, all 16 channels -> bf16 hi record, 2 x b128 ----
    for (int e = threadIdx.x; e < 18 * 66; e += 256) {
        const int r   = e / 66;
        const int col = e - r * 66;
        const int gy  = y0 - 1 + r;
        const int gx  = x0 - 1 + col;
        const bool ok = (gy >= 0) && (gy < HD) && (gx >= 0) && (gx < WD);
        const float* px = x + ((size_t)b * CD * HD * WD) + (size_t)gy * WD + gx;
        unsigned d[8];
        #pragma unroll
        for (int j = 0; j < 8; ++j) {
            float v0 = 0.f, v1 = 0.f;
            if (ok) {
                v0 = px[(size_t)(2 * j)     * (HD * WD)];
                v1 = px[(size_t)(2 * j + 1) * (HD * WD)];
            }
            d[j] = (unsigned)bf16_rne(v0) | ((unsigned)bf16_rne(v1) << 16);
        }
        unsigned* dst = reinterpret_cast<unsigned*>(&xs[e * 24]);
        *reinterpret_cast<uint4*>(dst)     = make_uint4(d[0], d[1], d[2], d[3]);
        *reinterpret_cast<uint4*>(dst + 4) = make_uint4(d[4], d[5], d[6], d[7]);
    }

    const int lane = threadIdx.x & 63;
    const int wv   = threadIdx.x >> 6;

    // ---- weight fragments: registers, straight from g_wfrag ----
    short8v whi[5], wlo[5];
    {
        const unsigned short* wf = g_wfrag + b * 5120;
        #pragma unroll
        for (int s = 0; s < 5; ++s) {
            whi[s] = *(const short8v*)&wf[s * 512 + lane * 8];
            wlo[s] = *(const short8v*)&wf[2560 + s * 512 + lane * 8];
        }
    }

    // ---- per-lane A addressing (A map HW-verified R7): m=lane&15 pixel,
    //      kk=(lane>>4)*8+i; tl=kg>>1 tap_local, chalf=kg&1 channel half ----
    const int m     = lane & 15;
    const int kg    = lane >> 4;
    const int tl    = kg >> 1;
    const int chalf = kg & 1;
    int aoff[5];
    #pragma unroll
    for (int s = 0; s < 5; ++s) {
        int tap = 2 * s + tl;
        if (tap > 8) tap = 8;             // pad-tap reads valid data; weights are 0
        const int dy = tap / 3 - 1, dx = tap % 3 - 1;
        aoff[s] = (dy * 66 + dx) * 24;    // u16 units
    }
    const int colbase = 1 + 16 * wv + m;

    __syncthreads();

    // ---- compute: 16 rows per wave, processed in pairs (2 acc chains) ----
    #pragma unroll 1
    for (int q2 = 0; q2 < 8; ++q2) {
        const int qa = 2 * q2;
        const int pa = ((qa + 1) * 66 + colbase) * 24 + chalf * 8;
        const int pb = pa + 66 * 24;
        float4v acca = {0.f, 0.f, 0.f, 0.f};
        float4v accb = {0.f, 0.f, 0.f, 0.f};
        #pragma unroll
        for (int s = 0; s < 5; ++s) {
            const short8v Aa = *(const short8v*)&xs[pa + aoff[s]];
            const short8v Ab = *(const short8v*)&xs[pb + aoff[s]];
            acca = __builtin_amdgcn_mfma_f32_16x16x32_bf16(Aa, whi[s], acca, 0, 0, 0);
            accb = __builtin_amdgcn_mfma_f32_16x16x32_bf16(Ab, whi[s], accb, 0, 0, 0);
            acca = __builtin_amdgcn_mfma_f32_16x16x32_bf16(Aa, wlo[s], acca, 0, 0, 0);
            accb = __builtin_amdgcn_mfma_f32_16x16x32_bf16(Ab, wlo[s], accb, 0, 0, 0);
        }
        // D (HW-verified R7): o = lane&15, pixel = kg*4 + reg -> float4 store
        const int o  = lane & 15;
        const int xc = x0 + 16 * wv + kg * 4;
        float4 va = make_float4(acca[0], acca[1], acca[2], acca[3]);
        float4 vb = make_float4(accb[0], accb[1], accb[2], accb[3]);
        *reinterpret_cast<float4*>(
            &out[((size_t)(b * OD + o) * HD + (y0 + qa)) * WD + xc]) = va;
        *reinterpret_cast<float4*>(
            &out[((size_t)(b * OD + o) * HD + (y0 + qa + 1)) * WD + xc]) = vb;
    }
}

extern "C" void kernel_launch(void* const* d_in, const int* in_sizes, int n_in,
                              void* d_out, int out_size, void* d_ws, size_t ws_size,
                              hipStream_t stream) {
    (void)in_sizes; (void)n_in; (void)out_size; (void)d_ws; (void)ws_size;
    const float* x      = (const float*)d_in[0];
    const float* weight = (const float*)d_in[1];
    const float* w1     = (const float*)d_in[2];
    const float* b1     = (const float*)d_in[3];
    const float* w2     = (const float*)d_in[4];
    const float* b2     = (const float*)d_in[5];
    float* out = (float*)d_out;

    pool_kernel<<<2048, 256, 0, stream>>>(x);
    attn_agg_kernel<<<32, 256, 0, stream>>>(w1, b1, w2, b2, weight);
    conv_kernel<<<dim3(64, 32), 256, 0, stream>>>(x, out);
}

// Round 9
// 297.547 us; speedup vs baseline: 1.2408x; 1.0076x over previous
//
#include <hip/hip_runtime.h>

#define BD  32
#define CD  16
#define HD  256
#define WD  256
#define KD  4
#define OD  16
#define C4D 4

typedef __attribute__((ext_vector_type(8))) short short8v;   // 8 bf16 = 4 VGPR
typedef __attribute__((ext_vector_type(4))) float float4v;   // MFMA C/D

// Module-level scratch (no ws_size dependence). Fully overwritten every call.
__device__ float          g_partial[2048];                   // 4 partial sums per plane
__device__ unsigned short g_xbf[(size_t)BD * CD * HD * WD];  // bf16 copy of x (67 MB)
// Weight fragments in exact MFMA-B lane order: [b][prod(hi/lo)][kstep 5][lane 64][i 8]
__device__ unsigned short g_wfrag[BD * 2 * 5 * 64 * 8];

__device__ __forceinline__ unsigned short bf16_rne(float f) {
    unsigned u = __builtin_bit_cast(unsigned, f);
    u += 0x7FFFu + ((u >> 16) & 1u);
    return (unsigned short)(u >> 16);
}
__device__ __forceinline__ float bf16_to_f(unsigned short h) {
    unsigned u = ((unsigned)h) << 16;
    return __builtin_bit_cast(float, u);
}

// ---------------- Kernel 1: global average pool + bf16 emission ------------
// 2048 blocks (4 per plane), 16 fully-unrolled float4 loads/thread.
// BW-bound with idle VALU -> bf16 conversion of x is free here.
__global__ void pool_kernel(const float* __restrict__ x) {
    const int plane = blockIdx.x >> 2;          // 0..511  (b*16+c)
    const int part  = blockIdx.x & 3;
    const size_t base = (size_t)plane * (HD * WD) + part * (HD * WD / 4);
    const float4* xp4 = reinterpret_cast<const float4*>(x + base);

    float4 v[16];
    #pragma unroll
    for (int i = 0; i < 16; ++i) v[i] = xp4[threadIdx.x + i * 256];

    float s = 0.f;
    #pragma unroll
    for (int i = 0; i < 16; ++i) {
        s += (v[i].x + v[i].y) + (v[i].z + v[i].w);
        ushort4 h;
        h.x = bf16_rne(v[i].x); h.y = bf16_rne(v[i].y);
        h.z = bf16_rne(v[i].z); h.w = bf16_rne(v[i].w);
        *reinterpret_cast<ushort4*>(&g_xbf[base + (size_t)(threadIdx.x + i * 256) * 4]) = h;
    }

    __shared__ float red[256];
    red[threadIdx.x] = s;
    __syncthreads();
    for (int off = 128; off > 0; off >>= 1) {
        if (threadIdx.x < off) red[threadIdx.x] += red[threadIdx.x + off];
        __syncthreads();
    }
    if (threadIdx.x == 0) g_partial[blockIdx.x] = red[0];
}

// ---------------- Kernel 2: attn MLP + softmax + bf16 weight fragments -----
// 128 blocks: 4 blocks per sample, each covers a 1280-element e-chunk.
// B-frag lane map (16x16x32, HW-verified R7): o = lane&15, kk = (lane>>4)*8 + i.
__global__ void attn_agg_kernel(const float* __restrict__ w1, const float* __restrict__ b1,
                                const float* __restrict__ w2, const float* __restrict__ b2,
                                const float* __restrict__ weight) {
    const int b  = blockIdx.x >> 2;
    const int e0 = (blockIdx.x & 3) * 1280;

    float p[CD];
    #pragma unroll
    for (int c = 0; c < CD; ++c) {
        const int i0 = (b * CD + c) * 4;
        p[c] = (g_partial[i0] + g_partial[i0 + 1] + g_partial[i0 + 2] + g_partial[i0 + 3])
               * (1.f / (HD * WD));
    }

    float h[C4D];
    #pragma unroll
    for (int j = 0; j < C4D; ++j) {
        float s = b1[j];
        #pragma unroll
        for (int c = 0; c < CD; ++c) s = fmaf(p[c], w1[j * CD + c], s);
        h[j] = fmaxf(s, 0.f);
    }

    float lg[KD];
    float mx = -1e30f;
    #pragma unroll
    for (int k = 0; k < KD; ++k) {
        float s = b2[k];
        #pragma unroll
        for (int j = 0; j < C4D; ++j) s = fmaf(h[j], w2[k * C4D + j], s);
        lg[k] = s;
        mx = fmaxf(mx, s);
    }
    float se = 0.f;
    #pragma unroll
    for (int k = 0; k < KD; ++k) { lg[k] = expf(lg[k] - mx); se += lg[k]; }
    const float inv = 1.f / se;
    float at[KD];
    #pragma unroll
    for (int k = 0; k < KD; ++k) at[k] = lg[k] * inv;

    // e = ((prod*5 + s)*64 + lane)*8 + i ; kstep s covers taps {2s,2s+1} x 16c
    for (int e = e0 + threadIdx.x; e < e0 + 1280; e += 256) {
        const int prod = e / 2560;
        const int rem  = e % 2560;
        const int s    = rem / 512;
        const int lr   = rem % 512;
        const int lane = lr >> 3;
        const int i    = lr & 7;
        const int o    = lane & 15;
        const int kg   = lane >> 4;
        const int kk   = kg * 8 + i;
        const int tl   = kk >> 4;
        const int c    = kk & 15;
        const int tap  = 2 * s + tl;        // 0..9 (9 = padding)
        float v = 0.f;
        if (tap < 9) {
            #pragma unroll
            for (int k = 0; k < KD; ++k)
                v = fmaf(at[k], weight[((k * OD + o) * CD + c) * 9 + tap], v);
        }
        const unsigned short hi = bf16_rne(v);
        unsigned short val = hi;
        if (prod == 1) val = bf16_rne(v - bf16_to_f(hi));
        g_wfrag[b * 5120 + e] = val;
    }
}

// ---------------- Kernel 3: MFMA conv, 2-product (xhi*whi + xhi*wlo) -------
// Block = 16 rows x 64 cols. LDS records 48 B/px (2-way-free bank stride,
// proven R8). Staging now reads bf16 planes (g_xbf): per 4-px group, 16 uint2
// channel loads -> register interleave -> 8 ds_write_b128. No conversions.
__global__ __launch_bounds__(256, 2)
void conv_kernel(float* __restrict__ out) {
    const int b  = blockIdx.y;
    const int tx = blockIdx.x & 3;        // 64-col strip
    const int ty = blockIdx.x >> 2;       // 16-row strip
    const int x0 = tx * 64, y0 = ty * 16;

    __shared__ unsigned short xs[18 * 66 * 24];   // 57,024 B

    // ---- interior: 18 rows x 16 aligned 4-col groups ----
    for (int grp = threadIdx.x; grp < 288; grp += 256) {
        const int r  = grp >> 4;          // 0..17
        const int j  = grp & 15;          // 0..15
        const int gy = y0 - 1 + r;
        const int gx = x0 + 4 * j;        // always in [0,252]
        const bool ok = (gy >= 0) && (gy < HD);
        uint2 v[16];
        #pragma unroll
        for (int c = 0; c < 16; ++c) {
            v[c] = make_uint2(0u, 0u);
            if (ok)
                v[c] = *reinterpret_cast<const uint2*>(
                    &g_xbf[((size_t)(b * CD + c) * HD + gy) * WD + gx]);
        }
        #pragma unroll
        for (int p = 0; p < 4; ++p) {
            unsigned d[8];
            #pragma unroll
            for (int i = 0; i < 8; ++i) {
                const unsigned a0 = (p < 2) ? v[2 * i].x     : v[2 * i].y;
                const unsigned a1 = (p < 2) ? v[2 * i + 1].x : v[2 * i + 1].y;
                d[i] = (p & 1) ? ((a0 >> 16) | (a1 & 0xFFFF0000u))
                               : ((a0 & 0xFFFFu) | (a1 << 16));
            }
            const int e = r * 66 + 4 * j + 1 + p;
            unsigned* dst = reinterpret_cast<unsigned*>(&xs[e * 24]);
            *reinterpret_cast<uint4*>(dst)     = make_uint4(d[0], d[1], d[2], d[3]);
            *reinterpret_cast<uint4*>(dst + 4) = make_uint4(d[4], d[5], d[6], d[7]);
        }
    }
    // ---- halo cols (col 0 and 65): 36 records, scalar channel loads ----
    if (threadIdx.x < 36) {
        const int r   = threadIdx.x >> 1;
        const int col = (threadIdx.x & 1) ? 65 : 0;
        const int gy  = y0 - 1 + r;
        const int gx  = x0 - 1 + col;
        const bool ok = (gy >= 0) && (gy < HD) && (gx >= 0) && (gx < WD);
        unsigned d[8];
        #pragma unroll
        for (int i = 0; i < 8; ++i) {
            unsigned u0 = 0, u1 = 0;
            if (ok) {
                u0 = g_xbf[((size_t)(b * CD + 2 * i)     * HD + gy) * WD + gx];
                u1 = g_xbf[((size_t)(b * CD + 2 * i + 1) * HD + gy) * WD + gx];
            }
            d[i] = u0 | (u1 << 16);
        }
        const int e = r * 66 + col;
        unsigned* dst = reinterpret_cast<unsigned*>(&xs[e * 24]);
        *reinterpret_cast<uint4*>(dst)     = make_uint4(d[0], d[1], d[2], d[3]);
        *reinterpret_cast<uint4*>(dst + 4) = make_uint4(d[4], d[5], d[6], d[7]);
    }

    const int lane = threadIdx.x & 63;
    const int wv   = threadIdx.x >> 6;

    // ---- weight fragments: registers, straight from g_wfrag ----
    short8v whi[5], wlo[5];
    {
        const unsigned short* wf = g_wfrag + b * 5120;
        #pragma unroll
        for (int s = 0; s < 5; ++s) {
            whi[s] = *(const short8v*)&wf[s * 512 + lane * 8];
            wlo[s] = *(const short8v*)&wf[2560 + s * 512 + lane * 8];
        }
    }

    // ---- per-lane A addressing (HW-verified R7): m=lane&15 pixel,
    //      kk=(lane>>4)*8+i; tl tap_local, chalf channel half ----
    const int m     = lane & 15;
    const int kg    = lane >> 4;
    const int tl    = kg >> 1;
    const int chalf = kg & 1;
    int aoff[5];
    #pragma unroll
    for (int s = 0; s < 5; ++s) {
        int tap = 2 * s + tl;
        if (tap > 8) tap = 8;             // pad-tap reads valid data; weights are 0
        const int dy = tap / 3 - 1, dx = tap % 3 - 1;
        aoff[s] = (dy * 66 + dx) * 24;    // u16 units
    }
    const int colbase = 1 + 16 * wv + m;

    __syncthreads();

    // ---- compute: 16 rows per wave, in pairs (2 acc chains) ----
    #pragma unroll 1
    for (int q2 = 0; q2 < 8; ++q2) {
        const int qa = 2 * q2;
        const int pa = ((qa + 1) * 66 + colbase) * 24 + chalf * 8;
        const int pb = pa + 66 * 24;
        float4v acca = {0.f, 0.f, 0.f, 0.f};
        float4v accb = {0.f, 0.f, 0.f, 0.f};
        #pragma unroll
        for (int s = 0; s < 5; ++s) {
            const short8v Aa = *(const short8v*)&xs[pa + aoff[s]];
            const short8v Ab = *(const short8v*)&xs[pb + aoff[s]];
            acca = __builtin_amdgcn_mfma_f32_16x16x32_bf16(Aa, whi[s], acca, 0, 0, 0);
            accb = __builtin_amdgcn_mfma_f32_16x16x32_bf16(Ab, whi[s], accb, 0, 0, 0);
            acca = __builtin_amdgcn_mfma_f32_16x16x32_bf16(Aa, wlo[s], acca, 0, 0, 0);
            accb = __builtin_amdgcn_mfma_f32_16x16x32_bf16(Ab, wlo[s], accb, 0, 0, 0);
        }
        // D (HW-verified R7): o = lane&15, pixel = kg*4 + reg -> float4 store
        const int o  = lane & 15;
        const int xc = x0 + 16 * wv + kg * 4;
        float4 va = make_float4(acca[0], acca[1], acca[2], acca[3]);
        float4 vb = make_float4(accb[0], accb[1], accb[2], accb[3]);
        *reinterpret_cast<float4*>(
            &out[((size_t)(b * OD + o) * HD + (y0 + qa)) * WD + xc]) = va;
        *reinterpret_cast<float4*>(
            &out[((size_t)(b * OD + o) * HD + (y0 + qa + 1)) * WD + xc]) = vb;
    }
}

extern "C" void kernel_launch(void* const* d_in, const int* in_sizes, int n_in,
                              void* d_out, int out_size, void* d_ws, size_t ws_size,
                              hipStream_t stream) {
    (void)in_sizes; (void)n_in; (void)out_size; (void)d_ws; (void)ws_size;
    const float* x      = (const float*)d_in[0];
    const float* weight = (const float*)d_in[1];
    const float* w1     = (const float*)d_in[2];
    const float* b1     = (const float*)d_in[3];
    const float* w2     = (const float*)d_in[4];
    const float* b2     = (const float*)d_in[5];
    float* out = (float*)d_out;

    pool_kernel<<<2048, 256, 0, stream>>>(x);
    attn_agg_kernel<<<128, 256, 0, stream>>>(w1, b1, w2, b2, weight);
    conv_kernel<<<dim3(64, 32), 256, 0, stream>>>(out);
}